// Round 11
// baseline (107.533 us; speedup 1.0000x reference)
//
#include <hip/hip_runtime.h>
#include <math.h>

// ws footprint: 50,331,648 bytes (decay table lives in the free region).
#define B_  2
#define T_  2048
#define C_  1024
#define NH_ 16
#define HD_ 64
#define N3_ 3072

typedef float f32x4 __attribute__((ext_vector_type(4)));
typedef float f32x16 __attribute__((ext_vector_type(16)));
typedef short bf16x8 __attribute__((ext_vector_type(8)));
typedef unsigned short u16;
typedef float f32x4_base __attribute__((ext_vector_type(4)));
typedef f32x4_base __attribute__((aligned(4))) f32x4u;   // 4B-aligned vector load

// Q prescale: 1/sqrt(64) * log2(e), so softmax uses exp2 directly.
#define QSCALE 0.18033688011112042f

#if __has_builtin(__builtin_amdgcn_exp2f)
#define EXP2(x) __builtin_amdgcn_exp2f(x)
#else
#define EXP2(x) exp2f(x)
#endif

__device__ __forceinline__ u16 f2bf(float x) {
  unsigned int u = __builtin_bit_cast(unsigned int, x);
  u += 0x7FFFu + ((u >> 16) & 1u);
  return (u16)(u >> 16);
}

__device__ __forceinline__ unsigned int cvt_pk_bf16(float lo, float hi) {
  unsigned int r;
  asm("v_cvt_pk_bf16_f32 %0, %1, %2" : "=v"(r) : "v"(lo), "v"(hi));
  return r;
}

#define GLD16(g, l) __builtin_amdgcn_global_load_lds( \
    (__attribute__((address_space(1))) void*)(g), \
    (__attribute__((address_space(3))) void*)(l), 16, 0, 0)

// ---------------- fused prep: x->bf16, Wa^T, Wp^T, decay table ----------------
__global__ __launch_bounds__(256) void prep_kernel(
    const float* __restrict__ x, u16* __restrict__ xb,
    const float* __restrict__ Wa, u16* __restrict__ WaT,
    const float* __restrict__ Wp, u16* __restrict__ WpT,
    float* __restrict__ decR)
{
  __shared__ float tile[32][33];
  const int bid = blockIdx.x;
  const int tid = threadIdx.x;
  if (bid < 4096) {
    int i = (bid * 256 + tid) * 4;
    float4 v = *(const float4*)(x + i);
    ushort4 o;
    o.x = f2bf(v.x); o.y = f2bf(v.y); o.z = f2bf(v.z); o.w = f2bf(v.w);
    *(ushort4*)(xb + i) = o;
  } else if (bid < 8192) {
    const float* in; u16* out; int Cc, c0, r0;
    if (bid < 7168) {
      int t = bid - 4096;
      in = Wa; out = WaT; Cc = N3_;
      c0 = (t % 96) * 32; r0 = (t / 96) * 32;
    } else {
      int t = bid - 7168;
      in = Wp; out = WpT; Cc = C_;
      c0 = (t % 32) * 32; r0 = (t / 32) * 32;
    }
    int tx = tid & 31, ty = tid >> 5;
#pragma unroll
    for (int rr = ty; rr < 32; rr += 8)
      tile[rr][tx] = in[(size_t)(r0 + rr) * Cc + c0 + tx];
    __syncthreads();
#pragma unroll
    for (int rr = ty; rr < 32; rr += 8)
      out[(size_t)(c0 + rr) * 1024 + r0 + tx] = f2bf(tile[tx][rr]);
  } else {
    int j = (bid - 8192) * 256 + tid;
    if (j < 4352) {
      int d = 2047 - j;
      float v = 1.0f;
      if (d >= 15) v = 1.0f - powf((float)(d - 15) * (1.0f / 2032.0f), 0.36787944117144233f);
      decR[j] = v;
    }
  }
}

// ---------------- GEMM: C[M][N] = A[M][K] * Bt[N][K]^T (unchanged R10) --------
template<int MODE>
__global__ __launch_bounds__(256, 3) void gemm128_kernel(
    const u16* __restrict__ A, const u16* __restrict__ Bt,
    float* __restrict__ Cf, u16* __restrict__ Cq, u16* __restrict__ Vt,
    int M, int N, int K)
{
  __shared__ char lds[49152];   // 3 bufs x (A 8KB + Bt 8KB)
  const int lane = threadIdx.x & 63;
  const int wave = threadIdx.x >> 6;
  const int nxb = N >> 7;
  const int orig = blockIdx.x;
  const int cpx = (int)gridDim.x >> 3;
  const int wg = (orig & 7) * cpx + (orig >> 3);
  const int m0 = (wg / nxb) << 7;
  const int n0 = (wg % nxb) << 7;
  const int wm = wave >> 1, wn = wave & 1;

  f32x4 acc[4][4] = {};

#define GSTAGE(buf, k0)                                                          \
  {                                                                              \
    _Pragma("unroll")                                                            \
    for (int c = 0; c < 2; ++c) {                                                \
      int chunk = wave * 2048 + c * 1024;                                        \
      int row = (chunk >> 6) + (lane >> 2);                                      \
      int wb = ((lane & 3) << 4) ^ ((row & 3) << 4);                             \
      GLD16((const char*)(A  + (size_t)(m0 + row) * K + (k0)) + wb,              \
            lds + (buf) * 16384 + chunk);                                        \
      GLD16((const char*)(Bt + (size_t)(n0 + row) * K + (k0)) + wb,              \
            lds + (buf) * 16384 + 8192 + chunk);                                 \
    }                                                                            \
  }

  const int nk = K >> 5;
  GSTAGE(0, 0);
  GSTAGE(1, 32);
  __syncthreads();

  for (int i = 0; i < nk; ++i) {
    if (i + 1 < nk) asm volatile("s_waitcnt vmcnt(4)" ::: "memory");
    else            asm volatile("s_waitcnt vmcnt(0)" ::: "memory");
    __builtin_amdgcn_s_barrier();
    __builtin_amdgcn_sched_barrier(0);
    if (i + 2 < nk) GSTAGE((i + 2) % 3, (i + 2) * 32);

    const char* base = lds + (i % 3) * 16384;
    bf16x8 af[4], bfr[4];
#pragma unroll
    for (int m = 0; m < 4; ++m) {
      int row = wm * 64 + m * 16 + (lane & 15);
      int wb = ((lane >> 4) << 4) ^ ((row & 3) << 4);
      af[m] = *(const bf16x8*)(base + row * 64 + wb);
    }
#pragma unroll
    for (int n = 0; n < 4; ++n) {
      int row = wn * 64 + n * 16 + (lane & 15);
      int wb = ((lane >> 4) << 4) ^ ((row & 3) << 4);
      bfr[n] = *(const bf16x8*)(base + 8192 + row * 64 + wb);
    }
    __builtin_amdgcn_s_setprio(1);
#pragma unroll
    for (int m = 0; m < 4; ++m)
#pragma unroll
      for (int n = 0; n < 4; ++n)
        acc[m][n] = __builtin_amdgcn_mfma_f32_16x16x32_bf16(af[m], bfr[n], acc[m][n], 0, 0, 0);
    __builtin_amdgcn_s_setprio(0);
  }

#pragma unroll
  for (int m = 0; m < 4; ++m) {
    int grow0 = m0 + wm * 64 + m * 16 + ((lane >> 4) << 2);
#pragma unroll
    for (int n = 0; n < 4; ++n) {
      int gcol = n0 + wn * 64 + n * 16 + (lane & 15);
      f32x4 v = acc[m][n];
      if (MODE == 0) {
        int bb = grow0 >> 11, tt0 = grow0 & 2047;
        int which = gcol >> 10, rem = gcol & 1023;
        int hh = rem >> 6, dd = rem & 63;
        if (which < 2) {
#pragma unroll
          for (int r = 0; r < 4; ++r) {
            float ov = (which == 0) ? v[r] * QSCALE : v[r];
            Cq[((size_t)(which * 32 + bb * 16 + hh) * 2048 + tt0 + r) * 64 + dd] = f2bf(ov);
          }
        } else {
          ushort4 o;
          o.x = f2bf(v[0]); o.y = f2bf(v[1]); o.z = f2bf(v[2]); o.w = f2bf(v[3]);
          *(ushort4*)(Vt + ((size_t)(bb * 16 + hh) * 64 + dd) * 2048 + tt0) = o;
        }
      } else {
#pragma unroll
        for (int r = 0; r < 4; ++r)
          Cf[(size_t)(grow0 + r) * N + gcol] = v[r];
      }
    }
  }
#undef GSTAGE
}

// ---------------- fused flash attention, 32x32 MFMA + in-register P ----------
// grid 512 = 2 blocks/CU, ALL co-resident (no dispatch tail). Block = 128-row
// q-tile, 4 waves x 32 q-rows; nkt = 2qt+2; CU-mates (orig, orig+256) get
// complementary qt (sum 15) and same bh -> 34 iters/CU uniform.
// S^T = mfma_32x32x16(K, Q): C col=q=lane&31, row=key=(r&3)+8(r>>2)+4hi [m74].
// P: cvt_pk pairs + v_permlane32_swap -> B-operand regs, NO LDS round-trip.
__global__ __launch_bounds__(256, 2) void attn_kernel(
    const u16* __restrict__ qkb, const u16* __restrict__ vtg,
    const float* __restrict__ decR, u16* __restrict__ yb)
{
  __shared__ char klds[2][8192];   // K tile [64 keys][128B d], XOR-swizzled
  __shared__ char vlds[2][8192];   // V^T tile [64 d][128B keys], XOR-swizzled

  const int lane = threadIdx.x & 63;
  const int wave = threadIdx.x >> 6;
  const int i31 = lane & 31;
  const int hi = lane >> 5;
  const int orig = blockIdx.x;
  const int xcd = orig & 7;
  const int j = orig >> 3;             // 0..63 within XCD
  const int bh = xcd * 4 + (j & 3);    // CU-mates (j, j+32): same bh
  const int tt = j >> 2;               // 0..15; CU-mates tt, tt+8
  const int qt = (tt < 8) ? tt : 23 - tt;   // qt(tt)+qt(tt+8) = 15
  const int b = bh >> 4, h = bh & 15;

  const u16* Q   = qkb + (size_t)bh * T_ * HD_;
  const u16* Kg  = qkb + (size_t)(32 + bh) * T_ * HD_;
  const u16* VTg = vtg + (size_t)bh * HD_ * T_;

  const int q = qt * 128 + wave * 32 + i31;   // this lane's q (S^T column)
  const float* dp = decR + (2047 - q) + hi * 4;

  // Q B-operand: B[k][n=q], lane holds Q[q][s*16 + hi*8 + j], j=0..7
  bf16x8 qa[4];
#pragma unroll
  for (int s = 0; s < 4; ++s)
    qa[s] = *(const bf16x8*)(Q + (size_t)q * HD_ + s * 16 + hi * 8);

  f32x16 accy[2] = {};     // y^T: row=d (db*32 + 8g+4hi+e), col=q
  f32x4 lsum4 = {};

#define ASTAGE(buf, kt)                                                          \
  {                                                                              \
    _Pragma("unroll")                                                            \
    for (int c = 0; c < 2; ++c) {                                                \
      int chunk = wave * 2048 + c * 1024;                                        \
      int row = (chunk >> 7) + (lane >> 3);                                      \
      int wb = ((lane & 7) << 4) ^ ((row & 7) << 4);                             \
      GLD16((const char*)(Kg + (size_t)((kt) * 64 + row) * HD_) + wb,            \
            klds[buf] + chunk);                                                  \
      GLD16((const char*)(VTg + (size_t)row * T_ + (kt) * 64) + wb,              \
            vlds[buf] + chunk);                                                  \
    }                                                                            \
  }

  // prologue: decay(0) prefetch + stage(0), one full drain
  f32x4 dc[8], dn[8];
#pragma unroll
  for (int g8 = 0; g8 < 8; ++g8)
    dn[g8] = *(const f32x4u*)(dp + (g8 >> 2) * 32 + (g8 & 3) * 8);
  ASTAGE(0, 0);
  __syncthreads();

  const int nkt = 2 * qt + 2;
  for (int kt = 0; kt < nkt; ++kt) {
    const int cur = kt & 1;
#pragma unroll
    for (int g8 = 0; g8 < 8; ++g8) dc[g8] = dn[g8];
    const float* dnx = dp + (kt + 1) * 64;
#pragma unroll
    for (int g8 = 0; g8 < 8; ++g8)
      dn[g8] = *(const f32x4u*)(dnx + (g8 >> 2) * 32 + (g8 & 3) * 8);
    // retires stage(kt)+decay(kt); stage(kt+1) not yet issued, decay(kt+1) in flight
    asm volatile("s_waitcnt vmcnt(8)" ::: "memory");
    __builtin_amdgcn_s_barrier();
    __builtin_amdgcn_sched_barrier(0);
    if (kt + 1 < nkt) ASTAGE(cur ^ 1, kt + 1);

    const bool active = (kt * 64 <= qt * 128 + wave * 32 + 31);
    if (active) {
      // S^T = K Q^T: A = K[key][dhead] from klds, B = Q regs
      f32x16 sacc[2] = {};
      __builtin_amdgcn_s_setprio(1);
#pragma unroll
      for (int kb = 0; kb < 2; ++kb) {
        int row = kb * 32 + i31;
        int swz = (row & 7) << 4;
#pragma unroll
        for (int s = 0; s < 4; ++s) {
          bf16x8 kf = *(const bf16x8*)(klds[cur] + row * 128 + ((s * 32 + hi * 16) ^ swz));
          sacc[kb] = __builtin_amdgcn_mfma_f32_32x32x16_bf16(kf, qa[s], sacc[kb], 0, 0, 0);
        }
      }
      __builtin_amdgcn_s_setprio(0);

      if (kt >= 2 * qt) {   // possibly-diagonal iters: mask key > q
#pragma unroll
        for (int kb = 0; kb < 2; ++kb)
#pragma unroll
          for (int r = 0; r < 16; ++r) {
            int key = kt * 64 + kb * 32 + (r & 3) + 8 * (r >> 2) + 4 * hi;
            sacc[kb][r] = (key > q) ? -1e30f : sacc[kb][r];
          }
      }

      // softmax: p = exp2(s); denom lane-local (col = q fixed per lane)
      unsigned int uu[2][4][2];
#pragma unroll
      for (int kb = 0; kb < 2; ++kb)
#pragma unroll
        for (int g = 0; g < 4; ++g) {
          f32x4 p;
#pragma unroll
          for (int e = 0; e < 4; ++e) p[e] = EXP2(sacc[kb][g * 4 + e]);
          lsum4 += p;
          f32x4 d4 = dc[kb * 4 + g];
          uu[kb][g][0] = cvt_pk_bf16(p[0] * d4[0], p[1] * d4[1]);
          uu[kb][g][1] = cvt_pk_bf16(p[2] * d4[2], p[3] * d4[3]);
        }

      // P -> B-operand regs via permlane32_swap (T12):
      // swap(A,C): A' = {A.lo, C.lo} (keys +0,+1 | +8,+9), C' = {A.hi, C.hi} (+4,+5 | +12,+13)
      bf16x8 pb[4];
#pragma unroll
      for (int s = 0; s < 4; ++s) {
        int kb = s >> 1, gg = (s & 1) * 2;
        unsigned int a  = uu[kb][gg][0],     b2 = uu[kb][gg][1];
        unsigned int c  = uu[kb][gg + 1][0], d2 = uu[kb][gg + 1][1];
        asm volatile("v_permlane32_swap_b32 %0, %1" : "+v"(a),  "+v"(c));
        asm volatile("v_permlane32_swap_b32 %0, %1" : "+v"(b2), "+v"(d2));
        int4 w; w.x = (int)a; w.y = (int)b2; w.z = (int)c; w.w = (int)d2;
        pb[s] = __builtin_bit_cast(bf16x8, w);
      }

      // y^T += V^T P: A = V^T[d][key] from vlds, B = pb regs
      __builtin_amdgcn_s_setprio(1);
#pragma unroll
      for (int db = 0; db < 2; ++db) {
        int row = db * 32 + i31;
        int swz = (row & 7) << 4;
#pragma unroll
        for (int s = 0; s < 4; ++s) {
          bf16x8 vf = *(const bf16x8*)(vlds[cur] + row * 128 + ((s * 32 + hi * 16) ^ swz));
          accy[db] = __builtin_amdgcn_mfma_f32_32x32x16_bf16(vf, pb[s], accy[db], 0, 0, 0);
        }
      }
      __builtin_amdgcn_s_setprio(0);
    }
  }
#undef ASTAGE

  // finalize: denom = own half + partner half (lanes l, l+32 share q)
  float lsum = (lsum4[0] + lsum4[1]) + (lsum4[2] + lsum4[3]);
  lsum += __shfl_xor(lsum, 32);
  const float rq = 1.0f / lsum;

  __syncthreads();   // all waves done reading klds -> safe to reuse as yt
  char* yt = (char*)klds + wave * 4096;   // wave-private [32 q][64 d] bf16
#pragma unroll
  for (int db = 0; db < 2; ++db)
#pragma unroll
    for (int g = 0; g < 4; ++g) {
      unsigned int w0 = cvt_pk_bf16(accy[db][g * 4 + 0] * rq, accy[db][g * 4 + 1] * rq);
      unsigned int w1 = cvt_pk_bf16(accy[db][g * 4 + 2] * rq, accy[db][g * 4 + 3] * rq);
      uint2 wv; wv.x = w0; wv.y = w1;
      *(uint2*)(yt + i31 * 128 + ((db * 64 + g * 16 + hi * 8) ^ ((i31 & 7) << 4))) = wv;
    }
  // coalesced store: lane pair (2r,2r+1) covers one q-row's 64 d values
  {
    int qloc = lane >> 1, dh = lane & 1;
    int tg = qt * 128 + wave * 32 + qloc;
    u16* dst = yb + ((size_t)b * T_ + tg) * 1024 + h * 64 + dh * 32;
#pragma unroll
    for (int c = 0; c < 4; ++c) {
      int colb = (dh * 64 + c * 16) ^ ((qloc & 7) << 4);
      int4 vv = *(const int4*)(yt + qloc * 128 + colb);
      *(int4*)(dst + c * 8) = vv;
    }
  }
}

// ---------------- launch ----------------
extern "C" void kernel_launch(void* const* d_in, const int* in_sizes, int n_in,
                              void* d_out, int out_size, void* d_ws, size_t ws_size,
                              hipStream_t stream) {
  const float* x  = (const float*)d_in[0];
  const float* Wa = (const float*)d_in[1];
  const float* Wp = (const float*)d_in[2];
  float* out = (float*)d_out;
  char* ws = (char*)d_ws;

  // workspace layout (bytes), total 50,331,648
  u16*   xb    = (u16*)(ws + 0);           //  8,388,608  x bf16; reused as yb
  u16*   WaT   = (u16*)(ws + 8388608);     //  6,291,456  W_attn^T bf16
  u16*   WpT   = (u16*)(ws + 14680064);    //  2,097,152  W_proj^T bf16
  u16*   qkb   = (u16*)(ws + 16777216);    // 16,777,216  Q,K bf16 [2][32][2048][64]
  float* decR  = (float*)(ws + 33554432);  //     17,408  reversed padded decay (4352)
  u16*   VT    = (u16*)(ws + 41943040);    //  8,388,608  V^T bf16 [32][64][2048]
  u16*   yb    = xb;

  prep_kernel<<<8209, 256, 0, stream>>>(x, xb, Wa, WaT, Wp, WpT, decR);
  gemm128_kernel<0><<<768, 256, 0, stream>>>(
      xb, WaT, nullptr, qkb, VT, B_ * T_, N3_, C_);
  attn_kernel<<<512, 256, 0, stream>>>(qkb, VT, decR, yb);
  gemm128_kernel<1><<<256, 256, 0, stream>>>(
      yb, WpT, out, nullptr, nullptr, B_ * T_, 1024, 1024);
}

// Round 12
// 103.843 us; speedup vs baseline: 1.0355x; 1.0355x over previous
//
#include <hip/hip_runtime.h>
#include <math.h>

// ws footprint: 50,331,648 bytes (decay table lives in the free region).
#define B_  2
#define T_  2048
#define C_  1024
#define NH_ 16
#define HD_ 64
#define N3_ 3072

typedef float f32x4 __attribute__((ext_vector_type(4)));
typedef short bf16x8 __attribute__((ext_vector_type(8)));
typedef unsigned short u16;
typedef float f32x4_base __attribute__((ext_vector_type(4)));
typedef f32x4_base __attribute__((aligned(4))) f32x4u;   // 4B-aligned vector load

// Q prescale: 1/sqrt(64) * log2(e), so softmax uses exp2 directly.
#define QSCALE 0.18033688011112042f

#if __has_builtin(__builtin_amdgcn_exp2f)
#define EXP2(x) __builtin_amdgcn_exp2f(x)
#else
#define EXP2(x) exp2f(x)
#endif

__device__ __forceinline__ u16 f2bf(float x) {
  unsigned int u = __builtin_bit_cast(unsigned int, x);
  u += 0x7FFFu + ((u >> 16) & 1u);
  return (u16)(u >> 16);
}

__device__ __forceinline__ unsigned int cvt_pk_bf16(float lo, float hi) {
  unsigned int r;
  asm("v_cvt_pk_bf16_f32 %0, %1, %2" : "=v"(r) : "v"(lo), "v"(hi));
  return r;
}

#define GLD16(g, l) __builtin_amdgcn_global_load_lds( \
    (__attribute__((address_space(1))) void*)(g), \
    (__attribute__((address_space(3))) void*)(l), 16, 0, 0)

// ---------------- fused prep: x->bf16, Wa^T, Wp^T, decay table ----------------
__global__ __launch_bounds__(256) void prep_kernel(
    const float* __restrict__ x, u16* __restrict__ xb,
    const float* __restrict__ Wa, u16* __restrict__ WaT,
    const float* __restrict__ Wp, u16* __restrict__ WpT,
    float* __restrict__ decR)
{
  __shared__ float tile[32][33];
  const int bid = blockIdx.x;
  const int tid = threadIdx.x;
  if (bid < 4096) {
    int i = (bid * 256 + tid) * 4;
    float4 v = *(const float4*)(x + i);
    ushort4 o;
    o.x = f2bf(v.x); o.y = f2bf(v.y); o.z = f2bf(v.z); o.w = f2bf(v.w);
    *(ushort4*)(xb + i) = o;
  } else if (bid < 8192) {
    const float* in; u16* out; int Cc, c0, r0;
    if (bid < 7168) {
      int t = bid - 4096;
      in = Wa; out = WaT; Cc = N3_;
      c0 = (t % 96) * 32; r0 = (t / 96) * 32;
    } else {
      int t = bid - 7168;
      in = Wp; out = WpT; Cc = C_;
      c0 = (t % 32) * 32; r0 = (t / 32) * 32;
    }
    int tx = tid & 31, ty = tid >> 5;
#pragma unroll
    for (int rr = ty; rr < 32; rr += 8)
      tile[rr][tx] = in[(size_t)(r0 + rr) * Cc + c0 + tx];
    __syncthreads();
#pragma unroll
    for (int rr = ty; rr < 32; rr += 8)
      out[(size_t)(c0 + rr) * 1024 + r0 + tx] = f2bf(tile[tx][rr]);
  } else {
    int j = (bid - 8192) * 256 + tid;
    if (j < 4352) {
      int d = 2047 - j;
      float v = 1.0f;
      if (d >= 15) v = 1.0f - powf((float)(d - 15) * (1.0f / 2032.0f), 0.36787944117144233f);
      decR[j] = v;
    }
  }
}

// ---------------- GEMM: C[M][N] = A[M][K] * Bt[N][K]^T (unchanged R10) --------
template<int MODE>
__global__ __launch_bounds__(256, 3) void gemm128_kernel(
    const u16* __restrict__ A, const u16* __restrict__ Bt,
    float* __restrict__ Cf, u16* __restrict__ Cq, u16* __restrict__ Vt,
    int M, int N, int K)
{
  __shared__ char lds[49152];   // 3 bufs x (A 8KB + Bt 8KB)
  const int lane = threadIdx.x & 63;
  const int wave = threadIdx.x >> 6;
  const int nxb = N >> 7;
  const int orig = blockIdx.x;
  const int cpx = (int)gridDim.x >> 3;
  const int wg = (orig & 7) * cpx + (orig >> 3);
  const int m0 = (wg / nxb) << 7;
  const int n0 = (wg % nxb) << 7;
  const int wm = wave >> 1, wn = wave & 1;

  f32x4 acc[4][4] = {};

#define GSTAGE(buf, k0)                                                          \
  {                                                                              \
    _Pragma("unroll")                                                            \
    for (int c = 0; c < 2; ++c) {                                                \
      int chunk = wave * 2048 + c * 1024;                                        \
      int row = (chunk >> 6) + (lane >> 2);                                      \
      int wb = ((lane & 3) << 4) ^ ((row & 3) << 4);                             \
      GLD16((const char*)(A  + (size_t)(m0 + row) * K + (k0)) + wb,              \
            lds + (buf) * 16384 + chunk);                                        \
      GLD16((const char*)(Bt + (size_t)(n0 + row) * K + (k0)) + wb,              \
            lds + (buf) * 16384 + 8192 + chunk);                                 \
    }                                                                            \
  }

  const int nk = K >> 5;
  GSTAGE(0, 0);
  GSTAGE(1, 32);
  __syncthreads();

  for (int i = 0; i < nk; ++i) {
    if (i + 1 < nk) asm volatile("s_waitcnt vmcnt(4)" ::: "memory");
    else            asm volatile("s_waitcnt vmcnt(0)" ::: "memory");
    __builtin_amdgcn_s_barrier();
    __builtin_amdgcn_sched_barrier(0);
    if (i + 2 < nk) GSTAGE((i + 2) % 3, (i + 2) * 32);

    const char* base = lds + (i % 3) * 16384;
    bf16x8 af[4], bfr[4];
#pragma unroll
    for (int m = 0; m < 4; ++m) {
      int row = wm * 64 + m * 16 + (lane & 15);
      int wb = ((lane >> 4) << 4) ^ ((row & 3) << 4);
      af[m] = *(const bf16x8*)(base + row * 64 + wb);
    }
#pragma unroll
    for (int n = 0; n < 4; ++n) {
      int row = wn * 64 + n * 16 + (lane & 15);
      int wb = ((lane >> 4) << 4) ^ ((row & 3) << 4);
      bfr[n] = *(const bf16x8*)(base + 8192 + row * 64 + wb);
    }
    __builtin_amdgcn_s_setprio(1);
#pragma unroll
    for (int m = 0; m < 4; ++m)
#pragma unroll
      for (int n = 0; n < 4; ++n)
        acc[m][n] = __builtin_amdgcn_mfma_f32_16x16x32_bf16(af[m], bfr[n], acc[m][n], 0, 0, 0);
    __builtin_amdgcn_s_setprio(0);
  }

#pragma unroll
  for (int m = 0; m < 4; ++m) {
    int grow0 = m0 + wm * 64 + m * 16 + ((lane >> 4) << 2);
#pragma unroll
    for (int n = 0; n < 4; ++n) {
      int gcol = n0 + wn * 64 + n * 16 + (lane & 15);
      f32x4 v = acc[m][n];
      if (MODE == 0) {
        int bb = grow0 >> 11, tt0 = grow0 & 2047;
        int which = gcol >> 10, rem = gcol & 1023;
        int hh = rem >> 6, dd = rem & 63;
        if (which < 2) {
#pragma unroll
          for (int r = 0; r < 4; ++r) {
            float ov = (which == 0) ? v[r] * QSCALE : v[r];
            Cq[((size_t)(which * 32 + bb * 16 + hh) * 2048 + tt0 + r) * 64 + dd] = f2bf(ov);
          }
        } else {
          ushort4 o;
          o.x = f2bf(v[0]); o.y = f2bf(v[1]); o.z = f2bf(v[2]); o.w = f2bf(v[3]);
          *(ushort4*)(Vt + ((size_t)(bb * 16 + hh) * 64 + dd) * 2048 + tt0) = o;
        }
      } else {
#pragma unroll
        for (int r = 0; r < 4; ++r)
          Cf[(size_t)(grow0 + r) * N + gcol] = v[r];
      }
    }
  }
#undef GSTAGE
}

// ---------------- fused flash attention with post-softmax decay ----------------
// ITERATION-UNIFORM blocks: grid 512 (2/CU), block = pair (qtA=x, qtB=31-x),
// 33 units of (tile, kt), ONE unit per iteration:
//   interleaved: (B,0),(A,0),(B,1),(A,1),...,(B,qtA),(A,qtA); tail: (B,kt) kt>qtA.
// Every block runs exactly 33 identical iterations -> all blocks co-resident for
// the whole kernel (8 waves/CU sustained), no heavy-tail, chains overlap.
// Tile kt staged at its first use (sel B), double-buffered; counted vmcnt(8).
// S^T = mfma(K,Q) 16x16: col=q=lane&15, row=key=quad*4+r (conflict-free frags).
__global__ __launch_bounds__(256, 2) void attn_kernel(
    const u16* __restrict__ qkb, const u16* __restrict__ vtg,
    const float* __restrict__ decR, u16* __restrict__ yb)
{
  __shared__ char klds[2][8192];   // K tile [64 keys][128B], XOR-swizzled
  __shared__ char vlds[2][8192];   // V^T tile [64 d][128B keys], XOR-swizzled
  __shared__ u16 plds[64 * 76];    // P [q][key], stride 76; shared by A/B (1 unit/iter)

  const int lane = threadIdx.x & 63;
  const int wave = threadIdx.x >> 6;
  const int quad = lane >> 4;
  const int l15 = lane & 15;
  const int orig = blockIdx.x;
  const int xcd = orig & 7;
  const int bh = xcd * 4 + ((orig >> 3) & 3);
  const int x = orig >> 5;             // 0..15 pair index
  const int qtA = x;
  const int qtB = 31 - x;
  const int b = bh >> 4, h = bh & 15;

  const u16* Q   = qkb + (size_t)bh * T_ * HD_;
  const u16* Kg  = qkb + (size_t)(32 + bh) * T_ * HD_;
  const u16* VTg = vtg + (size_t)bh * HD_ * T_;

  const int wrowB = qtB * 64 + wave * 16;
  const int wrowA = qtA * 64 + wave * 16;
  const int qB = wrowB + l15;
  const int qA = wrowA + l15;
  const float* dpB = decR + (2047 - qB + quad * 4);
  const float* dpA = decR + (2047 - qA + quad * 4);

  bf16x8 qaB[2], qaA[2];
  { const u16* qp = Q + (size_t)qB * HD_ + quad * 8;
    qaB[0] = *(const bf16x8*)qp; qaB[1] = *(const bf16x8*)(qp + 32); }
  { const u16* qp = Q + (size_t)qA * HD_ + quad * 8;
    qaA[0] = *(const bf16x8*)qp; qaA[1] = *(const bf16x8*)(qp + 32); }

  f32x4 accB[4] = {}, accA[4] = {};
  float lsumB = 0.0f, lsumA = 0.0f;

#define ASTAGE(buf, kt)                                                          \
  {                                                                              \
    _Pragma("unroll")                                                            \
    for (int c = 0; c < 2; ++c) {                                                \
      int chunk = wave * 2048 + c * 1024;                                        \
      int row = (chunk >> 7) + (lane >> 3);                                      \
      int wb = ((lane & 7) << 4) ^ ((row & 7) << 4);                             \
      GLD16((const char*)(Kg + (size_t)((kt) * 64 + row) * HD_) + wb,            \
            klds[buf] + chunk);                                                  \
      GLD16((const char*)(VTg + (size_t)row * T_ + (kt) * 64) + wb,              \
            vlds[buf] + chunk);                                                  \
    }                                                                            \
  }

  const int twoA1 = 2 * qtA + 1;

  // prologue: decay(unit 0 = (B,0)) + stage(0), one full drain
  f32x4 dc[4], dn[4];
#pragma unroll
  for (int f = 0; f < 4; ++f) dn[f] = *(const f32x4u*)(dpB + f * 16);
  ASTAGE(0, 0);
  __syncthreads();

  for (int u = 0; u < 33; ++u) {
    const int kt   = (u <= twoA1) ? (u >> 1) : (u - qtA - 1);
    const int selA = (u <= twoA1) ? (u & 1) : 0;
    const int cur  = kt & 1;

    // rotate decay regs; prefetch decay for unit u+1 (ALWAYS 8 loads; table
    // padded to 4352 so the u==32 over-prefetch stays in bounds)
#pragma unroll
    for (int f = 0; f < 4; ++f) dc[f] = dn[f];
    {
      const int u1 = u + 1;
      const int kt1   = (u1 <= twoA1) ? (u1 >> 1) : (u1 - qtA - 1);
      const int selA1 = (u1 <= twoA1) ? (u1 & 1) : 0;
      const float* dnp = (selA1 ? dpA : dpB) + kt1 * 64;
#pragma unroll
      for (int f = 0; f < 4; ++f) dn[f] = *(const f32x4u*)(dnp + f * 16);
    }

    // retires stage(for tile kt) + decay(u); leaves decay(u+1) in flight
    asm volatile("s_waitcnt vmcnt(8)" ::: "memory");
    __builtin_amdgcn_s_barrier();
    __builtin_amdgcn_sched_barrier(0);
    if (!selA && kt < qtB) ASTAGE(cur ^ 1, kt + 1);   // stage at tile's first use

    // K fragments (conflict-free: rows span 16, swizzle period 8 -> 2-way free)
    bf16x8 kf[4][2];
#pragma unroll
    for (int f = 0; f < 4; ++f) {
      int krow = f * 16 + l15;
      int base = krow * 128;
      int msk = (krow & 7) << 4;
      kf[f][0] = *(const bf16x8*)(klds[cur] + base + ((quad * 16) ^ msk));
      kf[f][1] = *(const bf16x8*)(klds[cur] + base + ((64 + quad * 16) ^ msk));
    }

    // S^T = K Q^T (log2 domain): col=q=l15, row=key=f*16+quad*4+r
    const bf16x8 q0 = selA ? qaA[0] : qaB[0];
    const bf16x8 q1 = selA ? qaA[1] : qaB[1];
    f32x4 s[4];
    __builtin_amdgcn_s_setprio(1);
#pragma unroll
    for (int f = 0; f < 4; ++f) {
      f32x4 t = {};
      t = __builtin_amdgcn_mfma_f32_16x16x32_bf16(kf[f][0], q0, t, 0, 0, 0);
      t = __builtin_amdgcn_mfma_f32_16x16x32_bf16(kf[f][1], q1, t, 0, 0, 0);
      s[f] = t;
    }
    __builtin_amdgcn_s_setprio(0);

    // diagonal mask (wave-uniform branch)
    const int qtsel = selA ? qtA : qtB;
    if (kt == qtsel) {
      const int qsel = selA ? qA : qB;
#pragma unroll
      for (int f = 0; f < 4; ++f) {
        int key0 = kt * 64 + f * 16 + quad * 4;
#pragma unroll
        for (int r = 0; r < 4; ++r)
          if (key0 + r > qsel) s[f][r] = -1e30f;
      }
    }

    // softmax: denom = sum exp2(s); numerator = exp2(s)*decay -> packed bf16
    float ls = 0.0f;
#pragma unroll
    for (int f = 0; f < 4; ++f) {
      f32x4 p;
#pragma unroll
      for (int r = 0; r < 4; ++r) p[r] = EXP2(s[f][r]);
      ls += (p[0] + p[1]) + (p[2] + p[3]);
      unsigned int w0 = cvt_pk_bf16(p[0] * dc[f][0], p[1] * dc[f][1]);
      unsigned int w1 = cvt_pk_bf16(p[2] * dc[f][2], p[3] * dc[f][3]);
      uint2 wv; wv.x = w0; wv.y = w1;
      *(uint2*)(plds + (size_t)(wave * 16 + l15) * 76 + f * 16 + quad * 4) = wv;
    }
    if (selA) lsumA += ls; else lsumB += ls;

    // V fragments
    bf16x8 vf[4][2];
#pragma unroll
    for (int n = 0; n < 4; ++n) {
      int vrow = n * 16 + l15;
      int mskv = (vrow & 7) << 4;
#pragma unroll
      for (int ks = 0; ks < 2; ++ks)
        vf[n][ks] = *(const bf16x8*)(vlds[cur] + vrow * 128 + ((ks * 64 + quad * 16) ^ mskv));
    }

    // y += P @ V (plds rows wave-private; static acc indexing via branch)
    bf16x8 pa0 = *(const bf16x8*)(plds + (size_t)(wave * 16 + l15) * 76 + quad * 8);
    bf16x8 pa1 = *(const bf16x8*)(plds + (size_t)(wave * 16 + l15) * 76 + 32 + quad * 8);
    __builtin_amdgcn_s_setprio(1);
    if (selA) {
#pragma unroll
      for (int n = 0; n < 4; ++n) {
        accA[n] = __builtin_amdgcn_mfma_f32_16x16x32_bf16(pa0, vf[n][0], accA[n], 0, 0, 0);
        accA[n] = __builtin_amdgcn_mfma_f32_16x16x32_bf16(pa1, vf[n][1], accA[n], 0, 0, 0);
      }
    } else {
#pragma unroll
      for (int n = 0; n < 4; ++n) {
        accB[n] = __builtin_amdgcn_mfma_f32_16x16x32_bf16(pa0, vf[n][0], accB[n], 0, 0, 0);
        accB[n] = __builtin_amdgcn_mfma_f32_16x16x32_bf16(pa1, vf[n][1], accB[n], 0, 0, 0);
      }
    }
    __builtin_amdgcn_s_setprio(0);
    // no end-of-iter barrier: next iteration's wait+barrier provides the sync
  }
#undef ASTAGE

  // finalize: denom for q=l15 -> reduce across quads, broadcast to q=quad*4+r
  lsumB += __shfl_xor(lsumB, 16); lsumB += __shfl_xor(lsumB, 32);
  lsumA += __shfl_xor(lsumA, 16); lsumA += __shfl_xor(lsumA, 32);
  float rB[4], rA[4];
#pragma unroll
  for (int r = 0; r < 4; ++r) {
    rB[r] = 1.0f / __shfl(lsumB, quad * 4 + r, 16);
    rA[r] = 1.0f / __shfl(lsumA, quad * 4 + r, 16);
  }
#pragma unroll
  for (int n = 0; n < 4; ++n) {
    int d = h * 64 + n * 16 + l15;
#pragma unroll
    for (int r = 0; r < 4; ++r) {
      int tB = wrowB + quad * 4 + r;
      int tA = wrowA + quad * 4 + r;
      yb[((size_t)b * T_ + tB) * 1024 + d] = f2bf(accB[n][r] * rB[r]);
      yb[((size_t)b * T_ + tA) * 1024 + d] = f2bf(accA[n][r] * rA[r]);
    }
  }
}

// ---------------- launch ----------------
extern "C" void kernel_launch(void* const* d_in, const int* in_sizes, int n_in,
                              void* d_out, int out_size, void* d_ws, size_t ws_size,
                              hipStream_t stream) {
  const float* x  = (const float*)d_in[0];
  const float* Wa = (const float*)d_in[1];
  const float* Wp = (const float*)d_in[2];
  float* out = (float*)d_out;
  char* ws = (char*)d_ws;

  // workspace layout (bytes), total 50,331,648
  u16*   xb    = (u16*)(ws + 0);           //  8,388,608  x bf16; reused as yb
  u16*   WaT   = (u16*)(ws + 8388608);     //  6,291,456  W_attn^T bf16
  u16*   WpT   = (u16*)(ws + 14680064);    //  2,097,152  W_proj^T bf16
  u16*   qkb   = (u16*)(ws + 16777216);    // 16,777,216  Q,K bf16 [2][32][2048][64]
  float* decR  = (float*)(ws + 33554432);  //     17,408  reversed padded decay (4352)
  u16*   VT    = (u16*)(ws + 41943040);    //  8,388,608  V^T bf16 [32][64][2048]
  u16*   yb    = xb;

  prep_kernel<<<8209, 256, 0, stream>>>(x, xb, Wa, WaT, Wp, WpT, decR);
  gemm128_kernel<0><<<768, 256, 0, stream>>>(
      xb, WaT, nullptr, qkb, VT, B_ * T_, N3_, C_);
  attn_kernel<<<512, 256, 0, stream>>>(qkb, VT, decR, yb);
  gemm128_kernel<1><<<256, 256, 0, stream>>>(
      yb, WpT, out, nullptr, nullptr, B_ * T_, 1024, 1024);
}

// Round 14
// 101.153 us; speedup vs baseline: 1.0631x; 1.0266x over previous
//
#include <hip/hip_runtime.h>
#include <math.h>

// ws footprint: 50,331,648 bytes (decay table lives in the free region).
#define B_  2
#define T_  2048
#define C_  1024
#define NH_ 16
#define HD_ 64
#define N3_ 3072

typedef float f32x4 __attribute__((ext_vector_type(4)));
typedef short bf16x8 __attribute__((ext_vector_type(8)));
typedef unsigned short u16;
typedef float f32x4_base __attribute__((ext_vector_type(4)));
typedef f32x4_base __attribute__((aligned(4))) f32x4u;   // 4B-aligned vector load

// Q prescale: 1/sqrt(64) * log2(e), so softmax uses exp2 directly.
#define QSCALE 0.18033688011112042f

#if __has_builtin(__builtin_amdgcn_exp2f)
#define EXP2(x) __builtin_amdgcn_exp2f(x)
#else
#define EXP2(x) exp2f(x)
#endif

__device__ __forceinline__ u16 f2bf(float x) {
  unsigned int u = __builtin_bit_cast(unsigned int, x);
  u += 0x7FFFu + ((u >> 16) & 1u);
  return (u16)(u >> 16);
}

__device__ __forceinline__ unsigned int cvt_pk_bf16(float lo, float hi) {
  unsigned int r;
  asm("v_cvt_pk_bf16_f32 %0, %1, %2" : "=v"(r) : "v"(lo), "v"(hi));
  return r;
}

#define GLD16(g, l) __builtin_amdgcn_global_load_lds( \
    (__attribute__((address_space(1))) void*)(g), \
    (__attribute__((address_space(3))) void*)(l), 16, 0, 0)

// ---------------- fused prep: x->bf16, Wa^T, Wp^T, decay table ----------------
__global__ __launch_bounds__(256) void prep_kernel(
    const float* __restrict__ x, u16* __restrict__ xb,
    const float* __restrict__ Wa, u16* __restrict__ WaT,
    const float* __restrict__ Wp, u16* __restrict__ WpT,
    float* __restrict__ decR)
{
  __shared__ float tile[32][33];
  const int bid = blockIdx.x;
  const int tid = threadIdx.x;
  if (bid < 4096) {
    int i = (bid * 256 + tid) * 4;
    float4 v = *(const float4*)(x + i);
    ushort4 o;
    o.x = f2bf(v.x); o.y = f2bf(v.y); o.z = f2bf(v.z); o.w = f2bf(v.w);
    *(ushort4*)(xb + i) = o;
  } else if (bid < 8192) {
    const float* in; u16* out; int Cc, c0, r0;
    if (bid < 7168) {
      int t = bid - 4096;
      in = Wa; out = WaT; Cc = N3_;
      c0 = (t % 96) * 32; r0 = (t / 96) * 32;
    } else {
      int t = bid - 7168;
      in = Wp; out = WpT; Cc = C_;
      c0 = (t % 32) * 32; r0 = (t / 32) * 32;
    }
    int tx = tid & 31, ty = tid >> 5;
#pragma unroll
    for (int rr = ty; rr < 32; rr += 8)
      tile[rr][tx] = in[(size_t)(r0 + rr) * Cc + c0 + tx];
    __syncthreads();
#pragma unroll
    for (int rr = ty; rr < 32; rr += 8)
      out[(size_t)(c0 + rr) * 1024 + r0 + tx] = f2bf(tile[tx][rr]);
  } else {
    int j = (bid - 8192) * 256 + tid;
    if (j < 4352) {
      int d = 2047 - j;
      float v = 1.0f;
      if (d >= 15) v = 1.0f - powf((float)(d - 15) * (1.0f / 2032.0f), 0.36787944117144233f);
      decR[j] = v;
    }
  }
}

// ---------------- gemm0: 256x256 tile, BK=64, 8 waves, 8-phase schedule ------
// R14 fixes vs R13: (1) second K-half fragment reads at byte 64 (was 32 --
// read k=16..47 garbage); (2) staging is UNCONDITIONAL with tile index clamped
// &(nt-1): per-wave vmem FIFO is uniform every iteration, so vmcnt(4) always
// retires exactly {own A-tile, own B-tile} -- fixes the final-iteration race
// where A(15) was left in flight while phases 5-8 read it. Dummy re-stages hit
// buffers whose reads already completed (register-held since prior barrier).
__global__ void __launch_bounds__(512, 1) gemm256_kernel(
    const u16* __restrict__ A, const u16* __restrict__ Bt,
    u16* __restrict__ Cq, u16* __restrict__ Vt,
    int M, int N, int K)
{
  extern __shared__ char lds[];   // A: buf*32768 + half*16384; B: 65536 + same
  const int tid = threadIdx.x;
  const int lane = tid & 63;
  const int wave = tid >> 6;
  const int wm = wave >> 2;        // 0..1 (M half)
  const int wn = wave & 3;         // 0..3 (N quarter)
  const int quad = lane >> 4;
  const int l15 = lane & 15;
  const int nxb = N >> 8;
  const int orig = blockIdx.x;
  const int cpx = (int)gridDim.x >> 3;
  const int wg = (orig & 7) * cpx + (orig >> 3);
  const int m0 = (wg / nxb) << 8;
  const int n0 = (wg % nxb) << 8;

  f32x4 acc[8][4] = {};

  const int abase = wm * 16384;                    // + buf*32768
  const int bbase = 65536 + (wn >> 1) * 16384;     // + buf*32768
  const int brow0 = (wn & 1) * 64;

#define HSTAGE(arr, rowbase, tile, ldsoff)                                       \
  {                                                                              \
    _Pragma("unroll")                                                            \
    for (int p = 0; p < 2; ++p) {                                                \
      int chunk = p * 8192 + tid * 16;                                           \
      int row = chunk >> 7;                                                      \
      int colb = (chunk & 127) ^ ((row & 7) << 4);                               \
      GLD16((const char*)((arr) + (size_t)((rowbase) + row) * K + (size_t)(tile) * 64) + colb, \
            lds + (ldsoff) + chunk);                                             \
    }                                                                            \
  }

#define PHASE(mg, buf, BLOAD, WAIT, STAGE_STMT)                                  \
  {                                                                              \
    if (WAIT) asm volatile("s_waitcnt vmcnt(4)" ::: "memory");                   \
    __builtin_amdgcn_s_barrier();                                                \
    __builtin_amdgcn_sched_barrier(0);                                           \
    STAGE_STMT;                                                                  \
    if (BLOAD) {                                                                 \
      _Pragma("unroll")                                                          \
      for (int n = 0; n < 4; ++n) {                                              \
        int rl = brow0 + n * 16 + l15;                                           \
        int msk = (rl & 7) << 4;                                                 \
        bfr[n][0] = *(const bf16x8*)(lds + bbase + (buf) * 32768 + rl * 128 +    \
                                     ((quad * 16) ^ msk));                       \
        bfr[n][1] = *(const bf16x8*)(lds + bbase + (buf) * 32768 + rl * 128 +    \
                                     ((64 + quad * 16) ^ msk));                  \
      }                                                                          \
    }                                                                            \
    bf16x8 af[2][2];                                                             \
    _Pragma("unroll")                                                            \
    for (int mm = 0; mm < 2; ++mm) {                                             \
      int rl = (mg) * 32 + mm * 16 + l15;                                        \
      int msk = (rl & 7) << 4;                                                   \
      af[mm][0] = *(const bf16x8*)(lds + abase + (buf) * 32768 + rl * 128 +      \
                                   ((quad * 16) ^ msk));                         \
      af[mm][1] = *(const bf16x8*)(lds + abase + (buf) * 32768 + rl * 128 +      \
                                   ((64 + quad * 16) ^ msk));                    \
    }                                                                            \
    __builtin_amdgcn_s_setprio(1);                                               \
    _Pragma("unroll")                                                            \
    for (int mm = 0; mm < 2; ++mm)                                               \
      _Pragma("unroll")                                                          \
      for (int n = 0; n < 4; ++n) {                                              \
        acc[(mg) * 2 + mm][n] = __builtin_amdgcn_mfma_f32_16x16x32_bf16(         \
            af[mm][0], bfr[n][0], acc[(mg) * 2 + mm][n], 0, 0, 0);               \
        acc[(mg) * 2 + mm][n] = __builtin_amdgcn_mfma_f32_16x16x32_bf16(         \
            af[mm][1], bfr[n][1], acc[(mg) * 2 + mm][n], 0, 0, 0);               \
      }                                                                          \
    __builtin_amdgcn_s_setprio(0);                                               \
  }

  bf16x8 bfr[4][2];

  // prologue: B(0)+A(0) -> buf0, B(1) -> buf1-B
  HSTAGE(Bt, n0 + 0,   0, 65536 + 0);
  HSTAGE(Bt, n0 + 128, 0, 65536 + 16384);
  HSTAGE(A,  m0 + 0,   0, 0);
  HSTAGE(A,  m0 + 128, 0, 16384);
  HSTAGE(Bt, n0 + 0,   1, 65536 + 32768);
  HSTAGE(Bt, n0 + 128, 1, 65536 + 32768 + 16384);

  const int nt = K >> 6;        // 16 tiles
  const int tm = nt - 1;        // clamp mask (nt is a power of 2)
  for (int j = 0; j < nt / 2; ++j) {
    const int t1 = 2 * j + 1, t2 = (2 * j + 2) & tm, t3 = (2 * j + 3) & tm;
    // phases 1-4: compute tile 2j (buf0)
    PHASE(0, 0, true,  true,  HSTAGE(A, m0 + 0,   t1, 32768));
    PHASE(1, 0, false, false, HSTAGE(A, m0 + 128, t1, 32768 + 16384));
    PHASE(2, 0, false, false, HSTAGE(Bt, n0 + 0,   t2, 65536));
    PHASE(3, 0, false, false, HSTAGE(Bt, n0 + 128, t2, 65536 + 16384));
    // phases 5-8: compute tile 2j+1 (buf1)
    PHASE(0, 1, true,  true,  HSTAGE(A, m0 + 0,   t2, 0));
    PHASE(1, 1, false, false, HSTAGE(A, m0 + 128, t2, 16384));
    PHASE(2, 1, false, false, HSTAGE(Bt, n0 + 0,   t3, 65536 + 32768));
    PHASE(3, 1, false, false, HSTAGE(Bt, n0 + 128, t3, 65536 + 32768 + 16384));
  }
#undef PHASE
#undef HSTAGE

  // epilogue: scatter Q (prescaled), K into qkb; V transposed into VT
#pragma unroll
  for (int m = 0; m < 8; ++m) {
    int grow0 = m0 + wm * 128 + m * 16 + quad * 4;
#pragma unroll
    for (int n = 0; n < 4; ++n) {
      int gcol = n0 + wn * 64 + n * 16 + l15;
      f32x4 v = acc[m][n];
      int bb = grow0 >> 11, tt0 = grow0 & 2047;
      int which = gcol >> 10, rem = gcol & 1023;
      int hh = rem >> 6, dd = rem & 63;
      if (which < 2) {
#pragma unroll
        for (int r = 0; r < 4; ++r) {
          float ov = (which == 0) ? v[r] * QSCALE : v[r];
          Cq[((size_t)(which * 32 + bb * 16 + hh) * 2048 + tt0 + r) * 64 + dd] = f2bf(ov);
        }
      } else {
        ushort4 o;
        o.x = f2bf(v[0]); o.y = f2bf(v[1]); o.z = f2bf(v[2]); o.w = f2bf(v[3]);
        *(ushort4*)(Vt + ((size_t)(bb * 16 + hh) * 64 + dd) * 2048 + tt0) = o;
      }
    }
  }
}

// ---------------- gemm1: 128x128, counted vmcnt, fp32 out --------------------
__global__ __launch_bounds__(256, 3) void gemm128_kernel(
    const u16* __restrict__ A, const u16* __restrict__ Bt,
    float* __restrict__ Cf, int M, int N, int K)
{
  __shared__ char lds[49152];
  const int lane = threadIdx.x & 63;
  const int wave = threadIdx.x >> 6;
  const int nxb = N >> 7;
  const int orig = blockIdx.x;
  const int cpx = (int)gridDim.x >> 3;
  const int wg = (orig & 7) * cpx + (orig >> 3);
  const int m0 = (wg / nxb) << 7;
  const int n0 = (wg % nxb) << 7;
  const int wm = wave >> 1, wn = wave & 1;

  f32x4 acc[4][4] = {};

#define GSTAGE(buf, k0)                                                          \
  {                                                                              \
    _Pragma("unroll")                                                            \
    for (int c = 0; c < 2; ++c) {                                                \
      int chunk = wave * 2048 + c * 1024;                                        \
      int row = (chunk >> 6) + (lane >> 2);                                      \
      int wb = ((lane & 3) << 4) ^ ((row & 3) << 4);                             \
      GLD16((const char*)(A  + (size_t)(m0 + row) * K + (k0)) + wb,              \
            lds + (buf) * 16384 + chunk);                                        \
      GLD16((const char*)(Bt + (size_t)(n0 + row) * K + (k0)) + wb,              \
            lds + (buf) * 16384 + 8192 + chunk);                                 \
    }                                                                            \
  }

  const int nk = K >> 5;
  GSTAGE(0, 0);
  GSTAGE(1, 32);
  __syncthreads();

  for (int i = 0; i < nk; ++i) {
    if (i + 1 < nk) asm volatile("s_waitcnt vmcnt(4)" ::: "memory");
    else            asm volatile("s_waitcnt vmcnt(0)" ::: "memory");
    __builtin_amdgcn_s_barrier();
    __builtin_amdgcn_sched_barrier(0);
    if (i + 2 < nk) GSTAGE((i + 2) % 3, (i + 2) * 32);

    const char* base = lds + (i % 3) * 16384;
    bf16x8 af[4], bfr[4];
#pragma unroll
    for (int m = 0; m < 4; ++m) {
      int row = wm * 64 + m * 16 + (lane & 15);
      int wb = ((lane >> 4) << 4) ^ ((row & 3) << 4);
      af[m] = *(const bf16x8*)(base + row * 64 + wb);
    }
#pragma unroll
    for (int n = 0; n < 4; ++n) {
      int row = wn * 64 + n * 16 + (lane & 15);
      int wb = ((lane >> 4) << 4) ^ ((row & 3) << 4);
      bfr[n] = *(const bf16x8*)(base + 8192 + row * 64 + wb);
    }
    __builtin_amdgcn_s_setprio(1);
#pragma unroll
    for (int m = 0; m < 4; ++m)
#pragma unroll
      for (int n = 0; n < 4; ++n)
        acc[m][n] = __builtin_amdgcn_mfma_f32_16x16x32_bf16(af[m], bfr[n], acc[m][n], 0, 0, 0);
    __builtin_amdgcn_s_setprio(0);
  }

#pragma unroll
  for (int m = 0; m < 4; ++m) {
    int grow0 = m0 + wm * 64 + m * 16 + ((lane >> 4) << 2);
#pragma unroll
    for (int n = 0; n < 4; ++n) {
      int gcol = n0 + wn * 64 + n * 16 + (lane & 15);
      f32x4 v = acc[m][n];
#pragma unroll
      for (int r = 0; r < 4; ++r)
        Cf[(size_t)(grow0 + r) * N + gcol] = v[r];
    }
  }
#undef GSTAGE
}

// ---------------- fused flash attention (R12 structure, vmcnt(4)) -------------
__global__ __launch_bounds__(256, 2) void attn_kernel(
    const u16* __restrict__ qkb, const u16* __restrict__ vtg,
    const float* __restrict__ decR, u16* __restrict__ yb)
{
  __shared__ char klds[2][8192];   // K tile [64 keys][128B], XOR-swizzled
  __shared__ char vlds[2][8192];   // V^T tile [64 d][128B keys], XOR-swizzled
  __shared__ u16 plds[64 * 76];    // P [q][key], stride 76

  const int lane = threadIdx.x & 63;
  const int wave = threadIdx.x >> 6;
  const int quad = lane >> 4;
  const int l15 = lane & 15;
  const int orig = blockIdx.x;
  const int xcd = orig & 7;
  const int bh = xcd * 4 + ((orig >> 3) & 3);
  const int x = orig >> 5;             // 0..15 pair index
  const int qtA = x;
  const int qtB = 31 - x;
  const int b = bh >> 4, h = bh & 15;

  const u16* Q   = qkb + (size_t)bh * T_ * HD_;
  const u16* Kg  = qkb + (size_t)(32 + bh) * T_ * HD_;
  const u16* VTg = vtg + (size_t)bh * HD_ * T_;

  const int wrowB = qtB * 64 + wave * 16;
  const int wrowA = qtA * 64 + wave * 16;
  const int qB = wrowB + l15;
  const int qA = wrowA + l15;
  const float* dpB = decR + (2047 - qB + quad * 4);
  const float* dpA = decR + (2047 - qA + quad * 4);

  bf16x8 qaB[2], qaA[2];
  { const u16* qp = Q + (size_t)qB * HD_ + quad * 8;
    qaB[0] = *(const bf16x8*)qp; qaB[1] = *(const bf16x8*)(qp + 32); }
  { const u16* qp = Q + (size_t)qA * HD_ + quad * 8;
    qaA[0] = *(const bf16x8*)qp; qaA[1] = *(const bf16x8*)(qp + 32); }

  f32x4 accB[4] = {}, accA[4] = {};
  float lsumB = 0.0f, lsumA = 0.0f;

#define ASTAGE(buf, kt)                                                          \
  {                                                                              \
    _Pragma("unroll")                                                            \
    for (int c = 0; c < 2; ++c) {                                                \
      int chunk = wave * 2048 + c * 1024;                                        \
      int row = (chunk >> 7) + (lane >> 3);                                      \
      int wb = ((lane & 7) << 4) ^ ((row & 7) << 4);                             \
      GLD16((const char*)(Kg + (size_t)((kt) * 64 + row) * HD_) + wb,            \
            klds[buf] + chunk);                                                  \
      GLD16((const char*)(VTg + (size_t)row * T_ + (kt) * 64) + wb,              \
            vlds[buf] + chunk);                                                  \
    }                                                                            \
  }

  const int twoA1 = 2 * qtA + 1;

  f32x4 dc[4], dn[4];
#pragma unroll
  for (int f = 0; f < 4; ++f) dn[f] = *(const f32x4u*)(dpB + f * 16);
  ASTAGE(0, 0);
  __syncthreads();

  for (int u = 0; u < 33; ++u) {
    const int kt   = (u <= twoA1) ? (u >> 1) : (u - qtA - 1);
    const int selA = (u <= twoA1) ? (u & 1) : 0;
    const int cur  = kt & 1;

#pragma unroll
    for (int f = 0; f < 4; ++f) dc[f] = dn[f];
    {
      const int u1 = u + 1;
      const int kt1   = (u1 <= twoA1) ? (u1 >> 1) : (u1 - qtA - 1);
      const int selA1 = (u1 <= twoA1) ? (u1 & 1) : 0;
      const float* dnp = (selA1 ? dpA : dpB) + kt1 * 64;
#pragma unroll
      for (int f = 0; f < 4; ++f) dn[f] = *(const f32x4u*)(dnp + f * 16);
    }

    // retire the staged tile + decay(u); keep only decay(u+1) in flight
    asm volatile("s_waitcnt vmcnt(4)" ::: "memory");
    __builtin_amdgcn_s_barrier();
    __builtin_amdgcn_sched_barrier(0);
    if (!selA && kt < qtB) ASTAGE(cur ^ 1, kt + 1);

    bf16x8 kf[4][2];
#pragma unroll
    for (int f = 0; f < 4; ++f) {
      int krow = f * 16 + l15;
      int base = krow * 128;
      int msk = (krow & 7) << 4;
      kf[f][0] = *(const bf16x8*)(klds[cur] + base + ((quad * 16) ^ msk));
      kf[f][1] = *(const bf16x8*)(klds[cur] + base + ((64 + quad * 16) ^ msk));
    }

    const bf16x8 q0 = selA ? qaA[0] : qaB[0];
    const bf16x8 q1 = selA ? qaA[1] : qaB[1];
    f32x4 s[4];
    __builtin_amdgcn_s_setprio(1);
#pragma unroll
    for (int f = 0; f < 4; ++f) {
      f32x4 t = {};
      t = __builtin_amdgcn_mfma_f32_16x16x32_bf16(kf[f][0], q0, t, 0, 0, 0);
      t = __builtin_amdgcn_mfma_f32_16x16x32_bf16(kf[f][1], q1, t, 0, 0, 0);
      s[f] = t;
    }
    __builtin_amdgcn_s_setprio(0);

    const int qtsel = selA ? qtA : qtB;
    if (kt == qtsel) {
      const int qsel = selA ? qA : qB;
#pragma unroll
      for (int f = 0; f < 4; ++f) {
        int key0 = kt * 64 + f * 16 + quad * 4;
#pragma unroll
        for (int r = 0; r < 4; ++r)
          if (key0 + r > qsel) s[f][r] = -1e30f;
      }
    }

    float ls = 0.0f;
#pragma unroll
    for (int f = 0; f < 4; ++f) {
      f32x4 p;
#pragma unroll
      for (int r = 0; r < 4; ++r) p[r] = EXP2(s[f][r]);
      ls += (p[0] + p[1]) + (p[2] + p[3]);
      unsigned int w0 = cvt_pk_bf16(p[0] * dc[f][0], p[1] * dc[f][1]);
      unsigned int w1 = cvt_pk_bf16(p[2] * dc[f][2], p[3] * dc[f][3]);
      uint2 wv; wv.x = w0; wv.y = w1;
      *(uint2*)(plds + (size_t)(wave * 16 + l15) * 76 + f * 16 + quad * 4) = wv;
    }
    if (selA) lsumA += ls; else lsumB += ls;

    bf16x8 vf[4][2];
#pragma unroll
    for (int n = 0; n < 4; ++n) {
      int vrow = n * 16 + l15;
      int mskv = (vrow & 7) << 4;
#pragma unroll
      for (int ks = 0; ks < 2; ++ks)
        vf[n][ks] = *(const bf16x8*)(vlds[cur] + vrow * 128 + ((ks * 64 + quad * 16) ^ mskv));
    }

    bf16x8 pa0 = *(const bf16x8*)(plds + (size_t)(wave * 16 + l15) * 76 + quad * 8);
    bf16x8 pa1 = *(const bf16x8*)(plds + (size_t)(wave * 16 + l15) * 76 + 32 + quad * 8);
    __builtin_amdgcn_s_setprio(1);
    if (selA) {
#pragma unroll
      for (int n = 0; n < 4; ++n) {
        accA[n] = __builtin_amdgcn_mfma_f32_16x16x32_bf16(pa0, vf[n][0], accA[n], 0, 0, 0);
        accA[n] = __builtin_amdgcn_mfma_f32_16x16x32_bf16(pa1, vf[n][1], accA[n], 0, 0, 0);
      }
    } else {
#pragma unroll
      for (int n = 0; n < 4; ++n) {
        accB[n] = __builtin_amdgcn_mfma_f32_16x16x32_bf16(pa0, vf[n][0], accB[n], 0, 0, 0);
        accB[n] = __builtin_amdgcn_mfma_f32_16x16x32_bf16(pa1, vf[n][1], accB[n], 0, 0, 0);
      }
    }
    __builtin_amdgcn_s_setprio(0);
  }
#undef ASTAGE

  lsumB += __shfl_xor(lsumB, 16); lsumB += __shfl_xor(lsumB, 32);
  lsumA += __shfl_xor(lsumA, 16); lsumA += __shfl_xor(lsumA, 32);
  float rB[4], rA[4];
#pragma unroll
  for (int r = 0; r < 4; ++r) {
    rB[r] = 1.0f / __shfl(lsumB, quad * 4 + r, 16);
    rA[r] = 1.0f / __shfl(lsumA, quad * 4 + r, 16);
  }
#pragma unroll
  for (int n = 0; n < 4; ++n) {
    int d = h * 64 + n * 16 + l15;
#pragma unroll
    for (int r = 0; r < 4; ++r) {
      int tB = wrowB + quad * 4 + r;
      int tA = wrowA + quad * 4 + r;
      yb[((size_t)b * T_ + tB) * 1024 + d] = f2bf(accB[n][r] * rB[r]);
      yb[((size_t)b * T_ + tA) * 1024 + d] = f2bf(accA[n][r] * rA[r]);
    }
  }
}

// ---------------- launch ----------------
extern "C" void kernel_launch(void* const* d_in, const int* in_sizes, int n_in,
                              void* d_out, int out_size, void* d_ws, size_t ws_size,
                              hipStream_t stream) {
  const float* x  = (const float*)d_in[0];
  const float* Wa = (const float*)d_in[1];
  const float* Wp = (const float*)d_in[2];
  float* out = (float*)d_out;
  char* ws = (char*)d_ws;

  // workspace layout (bytes), total 50,331,648
  u16*   xb    = (u16*)(ws + 0);           //  8,388,608  x bf16; reused as yb
  u16*   WaT   = (u16*)(ws + 8388608);     //  6,291,456  W_attn^T bf16
  u16*   WpT   = (u16*)(ws + 14680064);    //  2,097,152  W_proj^T bf16
  u16*   qkb   = (u16*)(ws + 16777216);    // 16,777,216  Q,K bf16 [2][32][2048][64]
  float* decR  = (float*)(ws + 33554432);  //     17,408  reversed padded decay (4352)
  u16*   VT    = (u16*)(ws + 41943040);    //  8,388,608  V^T bf16 [32][64][2048]
  u16*   yb    = xb;

  // unconditional (deterministic, idempotent; not a stream op)
  hipFuncSetAttribute((const void*)gemm256_kernel,
                      hipFuncAttributeMaxDynamicSharedMemorySize, 131072);

  prep_kernel<<<8209, 256, 0, stream>>>(x, xb, Wa, WaT, Wp, WpT, decR);
  gemm256_kernel<<<192, 512, 131072, stream>>>(xb, WaT, qkb, VT, B_ * T_, N3_, C_);
  attn_kernel<<<512, 256, 0, stream>>>(qkb, VT, decR, yb);
  gemm128_kernel<<<256, 256, 0, stream>>>(yb, WpT, out, B_ * T_, 1024, 1024);
}